// Round 7
// baseline (584.701 us; speedup 1.0000x reference)
//
#include <hip/hip_runtime.h>
#include <hip/hip_bf16.h>
#include <stdint.h>
#include <math.h>

#define IN_DIM 256
#define HID_DIM 256
#define OUT_DIM 128

typedef __attribute__((ext_vector_type(8))) short short8;
typedef __attribute__((ext_vector_type(4))) float floatx4;

__device__ __forceinline__ float bf2f(ushort u) {
  union { uint32_t i; float f; } v; v.i = ((uint32_t)u) << 16; return v.f;
}
__device__ __forceinline__ ushort f2bf(float f) {
  union { float f; uint32_t u; } v; v.f = f;
  uint32_t u = v.u;
  uint32_t r = u + 0x7fffu + ((u >> 16) & 1u);  // RNE; finite values only here
  return (ushort)(r >> 16);
}

// ---- dispatch A: degree counting (2 edges/thread) || W1T/WcT/bcat prep || fcW->bf16 ----
__global__ void deg_prep_kernel(const int* __restrict__ src, const int* __restrict__ dst,
                                int* __restrict__ out_deg, int* __restrict__ in_deg,
                                int E, int eblocks,
                                const float* __restrict__ W1, const float* __restrict__ W2,
                                const float* __restrict__ W3, const float* __restrict__ b2,
                                const float* __restrict__ b3, const float* __restrict__ fcW,
                                ushort* __restrict__ W1T, ushort* __restrict__ WcT,
                                float* __restrict__ bcat, ushort* __restrict__ fcWb) {
  int b = blockIdx.x, t = threadIdx.x;
  if (b < eblocks) {
    int e = (b * 256 + t) * 2;
    if (e + 1 < E) {
      int2 s = *(const int2*)(src + e);
      int2 d = *(const int2*)(dst + e);
      atomicAdd(&out_deg[s.x], 1);
      atomicAdd(&out_deg[s.y], 1);
      atomicAdd(&in_deg[d.x], 1);
      atomicAdd(&in_deg[d.y], 1);
    } else if (e < E) {
      atomicAdd(&out_deg[src[e]], 1);
      atomicAdd(&in_deg[dst[e]], 1);
    }
  } else if (b < eblocks + 256) {
    int k = b - eblocks;  // 0..255
    int nn = t;           // 0..255
    W1T[nn * 256 + k] = f2bf(W1[k * 256 + nn]);
    WcT[nn * 256 + k] = f2bf((nn < 128) ? W2[k * 128 + nn] : W3[k * 128 + (nn - 128)]);
    if (k == 0) bcat[nn] = (nn < 128) ? b2[nn] : b3[nn - 128];
  } else {
    int k = b - eblocks - 256;  // 0..255 (row of fcW)
    fcWb[k * 256 + t] = f2bf(fcW[k * 256 + t]);   // straight bf16 copy, coalesced
  }
}

// ---- MEGA: block 0 = scan(in_deg->row_ptr, batched int4);
//      blocks [1,1+gb)      = seq_fts GEMM (A=features fp32->bf16, B=fcWb bf16, C fp32)
//      blocks [1+gb,1+2gb)  = XW1 GEMM    (A=features fp32->bf16, B=W1T  bf16, C bf16)
// LDS: stride-64 XOR-swizzled (sc = c ^ ((row&7)<<3), same involution on write+read)
//      A 16KB + B 32KB = 48KB -> 3 blocks/CU
__global__ __launch_bounds__(256, 3) void mega_kernel(
    const float* __restrict__ feat, const ushort* __restrict__ fcWb,
    const ushort* __restrict__ W1T,
    float* __restrict__ s_out, ushort* __restrict__ xw1_bf,
    const int* __restrict__ in_deg, int* __restrict__ row_ptr, int n, int M, int gb) {
  __shared__ alignas(16) ushort A_lds[128 * 64];
  __shared__ alignas(16) ushort B_lds[256 * 64];
  int b = blockIdx.x;
  int t = threadIdx.x;

  if (b == 0) {
    // ============ scan role: latency-batched (8 int4 loads in flight) ============
    int* lds = (int*)A_lds;
    int CH = (n + 255) >> 8; CH = (CH + 3) & ~3;   // elems/thread, mult of 4
    int base = t * CH;
    int s = 0;
    if (base + CH <= n) {
      const int4* p = (const int4*)(in_deg + base);
      int c4 = CH >> 2;
#pragma unroll 8
      for (int j = 0; j < c4; ++j) { int4 q = p[j]; s += q.x + q.y + q.z + q.w; }
    } else {
      for (int i = base; i < n; ++i) s += in_deg[i];
    }
    lds[t] = s;
    __syncthreads();
    for (int off = 1; off < 256; off <<= 1) {
      int add = (t >= off) ? lds[t - off] : 0;
      __syncthreads();
      lds[t] += add;
      __syncthreads();
    }
    int run = lds[t] - s;                     // exclusive prefix
    if (t == 0) row_ptr[0] = 0;
    if (base + CH <= n) {
      const int4* p = (const int4*)(in_deg + base);
      int c4 = CH >> 2;
#pragma unroll 4
      for (int j = 0; j < c4; ++j) {
        int4 q = p[j];
        int i = base + j * 4;
        run += q.x; row_ptr[i + 1] = run;
        run += q.y; row_ptr[i + 2] = run;
        run += q.z; row_ptr[i + 3] = run;
        run += q.w; row_ptr[i + 4] = run;
      }
    } else {
      for (int i = base; i < n; ++i) { run += in_deg[i]; row_ptr[i + 1] = run; }
    }
    return;
  }

  // ============ GEMM roles (unified; only B source + epilogue differ) ============
  int bb = b - 1;
  bool isSeq = bb < gb;
  int m0 = (isSeq ? bb : bb - gb) * 128;
  const ushort* Bsrc = isSeq ? fcWb : W1T;
  int wave = t >> 6, lane = t & 63;
  int wm = wave * 32;
  int l15 = lane & 15, quad = lane >> 4;

  floatx4 acc[2][16];
#pragma unroll
  for (int i = 0; i < 2; ++i)
#pragma unroll
    for (int j = 0; j < 16; ++j) acc[i][j] = (floatx4)(0.f);

  for (int kc = 0; kc < 256; kc += 64) {
#pragma unroll
    for (int r = 0; r < 8; ++r) {   // A: features fp32 -> bf16 LDS (swizzled)
      int idx = t + r * 256;
      int row = idx >> 4;           // 0..127
      int c = (idx & 15) << 2;      // ushort offset 0..60
      int grow = m0 + row; if (grow > M - 1) grow = M - 1;
      float4 v = *(const float4*)(feat + (size_t)grow * 256 + kc + c);
      ushort4 o;
      o.x = f2bf(v.x); o.y = f2bf(v.y); o.z = f2bf(v.z); o.w = f2bf(v.w);
      int sc = c ^ ((row & 7) << 3);
      *(ushort4*)&A_lds[row * 64 + sc] = o;
    }
#pragma unroll
    for (int r = 0; r < 8; ++r) {   // B: bf16 copy (swizzled)
      int idx = t + r * 256;
      int row = idx >> 3;           // 0..255
      int c = (idx & 7) << 3;       // ushort offset 0..56
      int sc = c ^ ((row & 7) << 3);
      *(uint4*)&B_lds[row * 64 + sc] = *(const uint4*)(Bsrc + (size_t)row * 256 + kc + c);
    }
    __syncthreads();
#pragma unroll
    for (int ko = 0; ko < 2; ++ko) {
      short8 a[2];
#pragma unroll
      for (int i = 0; i < 2; ++i) {
        int row = wm + i * 16 + l15;
        int sc = (ko * 32 + quad * 8) ^ ((l15 & 7) << 3);   // row&7 == l15&7
        a[i] = *(const short8*)&A_lds[row * 64 + sc];
      }
#pragma unroll
      for (int j = 0; j < 16; ++j) {
        int brow = j * 16 + l15;
        int sc = (ko * 32 + quad * 8) ^ ((l15 & 7) << 3);
        short8 bv = *(const short8*)&B_lds[brow * 64 + sc];
#pragma unroll
        for (int i = 0; i < 2; ++i)
          acc[i][j] = __builtin_amdgcn_mfma_f32_16x16x32_bf16(a[i], bv, acc[i][j], 0, 0, 0);
      }
    }
    __syncthreads();
  }

  if (isSeq) {
#pragma unroll
    for (int i = 0; i < 2; ++i)
#pragma unroll
      for (int j = 0; j < 16; ++j) {
        int col = j * 16 + l15;
#pragma unroll
        for (int r = 0; r < 4; ++r) {
          int row = m0 + wm + i * 16 + quad * 4 + r;
          if (row < M) s_out[(size_t)row * 256 + col] = acc[i][j][r];
        }
      }
  } else {
#pragma unroll
    for (int i = 0; i < 2; ++i)
#pragma unroll
      for (int j = 0; j < 16; ++j) {
        int col = j * 16 + l15;
#pragma unroll
        for (int r = 0; r < 4; ++r) {
          int row = m0 + wm + i * 16 + quad * 4 + r;
          if (row < M) xw1_bf[(size_t)row * 256 + col] = f2bf(acc[i][j][r]);
        }
      }
  }
}

// ---- bucket edges by dst (CSR fill); 2 edges/thread; record {src, bits(rsqrt(out_deg))} ----
__global__ void fill_kernel(const int* __restrict__ src, const int* __restrict__ dst,
                            const int* __restrict__ row_ptr, int* __restrict__ fill_cnt,
                            const int* __restrict__ out_deg,
                            int2* __restrict__ edge_sw, int E) {
  int e = (blockIdx.x * 256 + threadIdx.x) * 2;
  if (e + 1 < E) {
    int2 s = *(const int2*)(src + e);
    int2 d = *(const int2*)(dst + e);
    int pos0 = row_ptr[d.x] + atomicAdd(&fill_cnt[d.x], 1);
    int od0 = out_deg[s.x]; if (od0 < 1) od0 = 1;
    int2 r0; r0.x = s.x; r0.y = __float_as_int(rsqrtf((float)od0));
    edge_sw[pos0] = r0;
    int pos1 = row_ptr[d.y] + atomicAdd(&fill_cnt[d.y], 1);
    int od1 = out_deg[s.y]; if (od1 < 1) od1 = 1;
    int2 r1; r1.x = s.y; r1.y = __float_as_int(rsqrtf((float)od1));
    edge_sw[pos1] = r1;
  } else if (e < E) {
    int d = dst[e]; int s = src[e];
    int pos = row_ptr[d] + atomicAdd(&fill_cnt[d], 1);
    int od = out_deg[s]; if (od < 1) od = 1;
    int2 r; r.x = s; r.y = __float_as_int(rsqrtf((float)od));
    edge_sw[pos] = r;
  }
}

// ---- aggregation over TRANSFORMED features with fused epilogue ----
// mode 0 (h):  out32[n][256] = relu(acc*inn + bias[dim]), outbf = bf16 copy
// mode 1 (z):  dims 0..127 = mean-part, 128..255 = logstd-part ->
//              z[n][c] = relu(am*inn+b2[c]) + noise[n][c]*exp(al*inn+b3[c])
__global__ __launch_bounds__(256) void agg_kernel(
    const ushort* __restrict__ x, const int* __restrict__ row_ptr,
    const int2* __restrict__ edge_sw,
    const float* __restrict__ bias, const float* __restrict__ noise,
    float* __restrict__ out32, ushort* __restrict__ outbf, int N, int mode) {
  int wave = threadIdx.x >> 6, lane = threadIdx.x & 63;
  int n = blockIdx.x * 4 + wave;
  if (n >= N) return;
  int half = lane >> 5;
  int hl = lane & 31;
  int start = row_ptr[n], end = row_ptr[n + 1];
  int dg = end - start; if (dg < 1) dg = 1;
  float inn = rsqrtf((float)dg);

  float acc[8];
#pragma unroll
  for (int k = 0; k < 8; ++k) acc[k] = 0.f;

  for (int base = start; base < end; base += 16) {
    int cs[8]; float cw[8];
    if (base + 16 <= end) {
#pragma unroll
      for (int k = 0; k < 8; ++k) {
        int2 e = edge_sw[base + half + 2 * k];
        cs[k] = e.x; cw[k] = __int_as_float(e.y);
      }
    } else {
#pragma unroll
      for (int k = 0; k < 8; ++k) {
        int i = base + half + 2 * k;
        cs[k] = 0; cw[k] = 0.f;
        if (i < end) { int2 e = edge_sw[i]; cs[k] = e.x; cw[k] = __int_as_float(e.y); }
      }
    }
    uint4 v[8];
#pragma unroll
    for (int k = 0; k < 8; ++k)
      v[k] = *(const uint4*)&x[(size_t)cs[k] * 256 + hl * 8];
#pragma unroll
    for (int k = 0; k < 8; ++k) {
      const uint32_t* p = (const uint32_t*)&v[k];
      float wk = cw[k];
#pragma unroll
      for (int q = 0; q < 4; ++q) {
        acc[2 * q]     += bf2f((ushort)(p[q] & 0xffffu)) * wk;
        acc[2 * q + 1] += bf2f((ushort)(p[q] >> 16)) * wk;
      }
    }
  }

#pragma unroll
  for (int k = 0; k < 8; ++k) acc[k] += __shfl_xor(acc[k], 32, 64);

  if (mode == 0) {
    if (half == 0) {
      int c0 = hl * 8;
      float4 ba = *(const float4*)(bias + c0);
      float4 bb = *(const float4*)(bias + c0 + 4);
      float h[8];
      h[0] = fmaxf(acc[0] * inn + ba.x, 0.f);
      h[1] = fmaxf(acc[1] * inn + ba.y, 0.f);
      h[2] = fmaxf(acc[2] * inn + ba.z, 0.f);
      h[3] = fmaxf(acc[3] * inn + ba.w, 0.f);
      h[4] = fmaxf(acc[4] * inn + bb.x, 0.f);
      h[5] = fmaxf(acc[5] * inn + bb.y, 0.f);
      h[6] = fmaxf(acc[6] * inn + bb.z, 0.f);
      h[7] = fmaxf(acc[7] * inn + bb.w, 0.f);
      *(float4*)&out32[(size_t)n * 256 + c0] = make_float4(h[0], h[1], h[2], h[3]);
      *(float4*)&out32[(size_t)n * 256 + c0 + 4] = make_float4(h[4], h[5], h[6], h[7]);
      uint4 ob; uint32_t* po = (uint32_t*)&ob;
#pragma unroll
      for (int q = 0; q < 4; ++q)
        po[q] = ((uint32_t)f2bf(h[2 * q + 1]) << 16) | (uint32_t)f2bf(h[2 * q]);
      *(uint4*)&outbf[(size_t)n * 256 + c0] = ob;
    }
  } else {
    float pacc[8];
#pragma unroll
    for (int k = 0; k < 8; ++k) pacc[k] = __shfl(acc[k], (lane & 15) + 16, 64);
    if (lane < 16) {
      int c0 = lane * 8;
      float4 b2a = *(const float4*)(bias + c0);
      float4 b2b = *(const float4*)(bias + c0 + 4);
      float4 b3a = *(const float4*)(bias + 128 + c0);
      float4 b3b = *(const float4*)(bias + 128 + c0 + 4);
      float4 nza = *(const float4*)(noise + (size_t)n * 128 + c0);
      float4 nzb = *(const float4*)(noise + (size_t)n * 128 + c0 + 4);
      float z[8];
      z[0] = fmaxf(acc[0] * inn + b2a.x, 0.f) + nza.x * expf(pacc[0] * inn + b3a.x);
      z[1] = fmaxf(acc[1] * inn + b2a.y, 0.f) + nza.y * expf(pacc[1] * inn + b3a.y);
      z[2] = fmaxf(acc[2] * inn + b2a.z, 0.f) + nza.z * expf(pacc[2] * inn + b3a.z);
      z[3] = fmaxf(acc[3] * inn + b2a.w, 0.f) + nza.w * expf(pacc[3] * inn + b3a.w);
      z[4] = fmaxf(acc[4] * inn + b2b.x, 0.f) + nzb.x * expf(pacc[4] * inn + b3b.x);
      z[5] = fmaxf(acc[5] * inn + b2b.y, 0.f) + nzb.y * expf(pacc[5] * inn + b3b.y);
      z[6] = fmaxf(acc[6] * inn + b2b.z, 0.f) + nzb.z * expf(pacc[6] * inn + b3b.z);
      z[7] = fmaxf(acc[7] * inn + b2b.w, 0.f) + nzb.w * expf(pacc[7] * inn + b3b.w);
      *(float4*)&out32[(size_t)n * 128 + c0] = make_float4(z[0], z[1], z[2], z[3]);
      *(float4*)&out32[(size_t)n * 128 + c0 + 4] = make_float4(z[4], z[5], z[6], z[7]);
    }
  }
}

// ---- MFMA GEMM: hwc = h_bf @ WcT, bf16 out, swizzled stride-64 LDS (48KB, 3 blocks/CU) ----
__global__ __launch_bounds__(256, 3) void gemm_bf_kernel(
    const ushort* __restrict__ A, const ushort* __restrict__ BT,
    ushort* __restrict__ Cbf, int M) {
  __shared__ alignas(16) ushort A_lds[128 * 64];
  __shared__ alignas(16) ushort B_lds[256 * 64];
  int t = threadIdx.x;
  int m0 = blockIdx.x * 128;
  int wave = t >> 6, lane = t & 63;
  int wm = wave * 32;
  int l15 = lane & 15, quad = lane >> 4;

  floatx4 acc[2][16];
#pragma unroll
  for (int i = 0; i < 2; ++i)
#pragma unroll
    for (int j = 0; j < 16; ++j) acc[i][j] = (floatx4)(0.f);

  for (int kc = 0; kc < 256; kc += 64) {
#pragma unroll
    for (int r = 0; r < 4; ++r) {         // A: 128 rows x 8 granules (swizzled)
      int idx = t + r * 256;
      int row = idx >> 3;
      int c = (idx & 7) << 3;
      int grow = m0 + row; if (grow > M - 1) grow = M - 1;
      int sc = c ^ ((row & 7) << 3);
      *(uint4*)&A_lds[row * 64 + sc] = *(const uint4*)(A + (size_t)grow * 256 + kc + c);
    }
#pragma unroll
    for (int r = 0; r < 8; ++r) {         // B: 256 rows x 8 granules (swizzled)
      int idx = t + r * 256;
      int row = idx >> 3;
      int c = (idx & 7) << 3;
      int sc = c ^ ((row & 7) << 3);
      *(uint4*)&B_lds[row * 64 + sc] = *(const uint4*)(BT + (size_t)row * 256 + kc + c);
    }
    __syncthreads();
#pragma unroll
    for (int ko = 0; ko < 2; ++ko) {
      short8 a[2];
#pragma unroll
      for (int i = 0; i < 2; ++i) {
        int row = wm + i * 16 + l15;
        int sc = (ko * 32 + quad * 8) ^ ((l15 & 7) << 3);
        a[i] = *(const short8*)&A_lds[row * 64 + sc];
      }
#pragma unroll
      for (int j = 0; j < 16; ++j) {
        int brow = j * 16 + l15;
        int sc = (ko * 32 + quad * 8) ^ ((l15 & 7) << 3);
        short8 bv = *(const short8*)&B_lds[brow * 64 + sc];
#pragma unroll
        for (int i = 0; i < 2; ++i)
          acc[i][j] = __builtin_amdgcn_mfma_f32_16x16x32_bf16(a[i], bv, acc[i][j], 0, 0, 0);
      }
    }
    __syncthreads();
  }

#pragma unroll
  for (int i = 0; i < 2; ++i)
#pragma unroll
    for (int j = 0; j < 16; ++j) {
      int col = j * 16 + l15;
#pragma unroll
      for (int r = 0; r < 4; ++r) {
        int row = m0 + wm + i * 16 + quad * 4 + r;
        if (row < M) Cbf[(size_t)row * 256 + col] = f2bf(acc[i][j][r]);
      }
    }
}

extern "C" void kernel_launch(void* const* d_in, const int* in_sizes, int n_in,
                              void* d_out, int out_size, void* d_ws, size_t ws_size,
                              hipStream_t stream) {
  const float* features = (const float*)d_in[0];
  const float* noise    = (const float*)d_in[1];
  const float* W1 = (const float*)d_in[2];
  const float* b1 = (const float*)d_in[3];
  const float* W2 = (const float*)d_in[4];
  const float* b2 = (const float*)d_in[5];
  const float* W3 = (const float*)d_in[6];
  const float* b3 = (const float*)d_in[7];
  const float* fcW = (const float*)d_in[8];
  const int* src = (const int*)d_in[9];
  const int* dst = (const int*)d_in[10];
  const int N = in_sizes[0] / IN_DIM;
  const int E = in_sizes[9];

  float* out = (float*)d_out;
  float* z_out = out;                           // N x 128
  float* h_out = out + (size_t)N * OUT_DIM;     // N x 256
  float* s_out = h_out + (size_t)N * HID_DIM;   // N x 256

  char* w = (char*)d_ws;
  auto carve = [&](size_t bytes) {
    char* p = w;
    w += (bytes + 255) & ~(size_t)255;
    return p;
  };
  ushort* xw1_bf = (ushort*)carve((size_t)N * 256 * 2);
  ushort* h_bf   = (ushort*)carve((size_t)N * 256 * 2);
  ushort* hwc_bf = (ushort*)carve((size_t)N * 256 * 2);
  ushort* W1T  = (ushort*)carve(256 * 256 * 2);
  ushort* WcT  = (ushort*)carve(256 * 256 * 2);
  ushort* fcWb = (ushort*)carve(256 * 256 * 2);
  float*  bcat = (float*)carve(256 * 4);
  int* degs    = (int*)carve((size_t)3 * N * 4);          // out_deg | in_deg | fill_cnt
  int* out_deg = degs;
  int* in_deg  = degs + N;
  int* fill_cnt = degs + 2 * N;
  int* row_ptr  = (int*)carve((size_t)(N + 1) * 4);
  int2* edge_sw = (int2*)carve((size_t)E * 8);

  hipMemsetAsync(degs, 0, (size_t)3 * N * 4, stream);
  int eblocks = ((E + 1) / 2 + 255) / 256;
  int gb = (N + 127) / 128;

  // A: degree atomics || W1T/WcT/bcat prep || fcW bf16 convert (all independent)
  deg_prep_kernel<<<eblocks + 512, 256, 0, stream>>>(src, dst, out_deg, in_deg, E, eblocks,
                                                     W1, W2, W3, b2, b3, fcW,
                                                     W1T, WcT, bcat, fcWb);
  // MEGA: scan || seq_fts GEMM || XW1 GEMM (W1T/fcWb ready from A)
  mega_kernel<<<2 * gb + 1, 256, 0, stream>>>(features, fcWb, W1T, s_out, xw1_bf,
                                              in_deg, row_ptr, N, N, gb);
  // CSR fill (needs row_ptr + out_deg)
  fill_kernel<<<eblocks, 256, 0, stream>>>(src, dst, row_ptr, fill_cnt, out_deg,
                                           edge_sw, E);
  // layer 1: h = relu(inn * agg(xw1) + b1)
  agg_kernel<<<(N + 3) / 4, 256, 0, stream>>>(xw1_bf, row_ptr, edge_sw, b1,
                                              (const float*)nullptr, h_out, h_bf, N, 0);
  // layer 2 dense part: hwc = h_bf @ [W2|W3]
  gemm_bf_kernel<<<gb, 256, 0, stream>>>(h_bf, WcT, hwc_bf, N);
  // layer 2 + reparam: z = relu(inn*agg(hwc_m)+b2) + noise*exp(inn*agg(hwc_l)+b3)
  agg_kernel<<<(N + 3) / 4, 256, 0, stream>>>(hwc_bf, row_ptr, edge_sw, bcat,
                                              noise, z_out, (ushort*)nullptr, N, 1);
}

// Round 8
// 492.943 us; speedup vs baseline: 1.1861x; 1.1861x over previous
//
#include <hip/hip_runtime.h>
#include <hip/hip_bf16.h>
#include <stdint.h>
#include <math.h>

#define IN_DIM 256
#define HID_DIM 256
#define OUT_DIM 128

typedef __attribute__((ext_vector_type(8))) short short8;
typedef __attribute__((ext_vector_type(4))) float floatx4;

__device__ __forceinline__ float bf2f(ushort u) {
  union { uint32_t i; float f; } v; v.i = ((uint32_t)u) << 16; return v.f;
}
__device__ __forceinline__ ushort f2bf(float f) {
  union { float f; uint32_t u; } v; v.f = f;
  uint32_t u = v.u;
  uint32_t r = u + 0x7fffu + ((u >> 16) & 1u);  // RNE; finite values only here
  return (ushort)(r >> 16);
}

// ---- dispatch A: degree counting (2 edges/thread) || W1T/WcT/bcat prep || fcW->bf16 ----
__global__ void deg_prep_kernel(const int* __restrict__ src, const int* __restrict__ dst,
                                int* __restrict__ out_deg, int* __restrict__ in_deg,
                                int E, int eblocks,
                                const float* __restrict__ W1, const float* __restrict__ W2,
                                const float* __restrict__ W3, const float* __restrict__ b2,
                                const float* __restrict__ b3, const float* __restrict__ fcW,
                                ushort* __restrict__ W1T, ushort* __restrict__ WcT,
                                float* __restrict__ bcat, ushort* __restrict__ fcWb) {
  int b = blockIdx.x, t = threadIdx.x;
  if (b < eblocks) {
    int e = (b * 256 + t) * 2;
    if (e + 1 < E) {
      int2 s = *(const int2*)(src + e);
      int2 d = *(const int2*)(dst + e);
      atomicAdd(&out_deg[s.x], 1);
      atomicAdd(&out_deg[s.y], 1);
      atomicAdd(&in_deg[d.x], 1);
      atomicAdd(&in_deg[d.y], 1);
    } else if (e < E) {
      atomicAdd(&out_deg[src[e]], 1);
      atomicAdd(&in_deg[dst[e]], 1);
    }
  } else if (b < eblocks + 256) {
    int k = b - eblocks;  // 0..255
    int nn = t;           // 0..255
    W1T[nn * 256 + k] = f2bf(W1[k * 256 + nn]);
    WcT[nn * 256 + k] = f2bf((nn < 128) ? W2[k * 128 + nn] : W3[k * 128 + (nn - 128)]);
    if (k == 0) bcat[nn] = (nn < 128) ? b2[nn] : b3[nn - 128];
  } else {
    int k = b - eblocks - 256;  // 0..255 (row of fcW)
    fcWb[k * 256 + t] = f2bf(fcW[k * 256 + t]);   // straight bf16 copy, coalesced
  }
}

// ---- MEGA: block 0 = scan(in_deg->row_ptr, batched int4);
//      blocks [1,1+gb)      = seq_fts GEMM (A=features fp32->bf16, B=fcWb bf16, C fp32)
//      blocks [1+gb,1+2gb)  = XW1 GEMM    (A=features fp32->bf16, B=W1T  bf16, C bf16)
// LDS: stride-64 XOR-swizzled, 48KB -> 3 blocks/CU from LDS alone.
// NOTE: launch_bounds min-waves stays at 2 -- forcing 3 starved the allocator to
// 84 VGPR (acc=128 floats) -> scratch spills -> +190MB HBM traffic (round-7 counters).
__global__ __launch_bounds__(256, 2) void mega_kernel(
    const float* __restrict__ feat, const ushort* __restrict__ fcWb,
    const ushort* __restrict__ W1T,
    float* __restrict__ s_out, ushort* __restrict__ xw1_bf,
    const int* __restrict__ in_deg, int* __restrict__ row_ptr, int n, int M, int gb) {
  __shared__ alignas(16) ushort A_lds[128 * 64];
  __shared__ alignas(16) ushort B_lds[256 * 64];
  int b = blockIdx.x;
  int t = threadIdx.x;

  if (b == 0) {
    // ============ scan role: latency-batched (8 int4 loads in flight) ============
    int* lds = (int*)A_lds;
    int CH = (n + 255) >> 8; CH = (CH + 3) & ~3;   // elems/thread, mult of 4
    int base = t * CH;
    int s = 0;
    if (base + CH <= n) {
      const int4* p = (const int4*)(in_deg + base);
      int c4 = CH >> 2;
#pragma unroll 8
      for (int j = 0; j < c4; ++j) { int4 q = p[j]; s += q.x + q.y + q.z + q.w; }
    } else {
      for (int i = base; i < n; ++i) s += in_deg[i];
    }
    lds[t] = s;
    __syncthreads();
    for (int off = 1; off < 256; off <<= 1) {
      int add = (t >= off) ? lds[t - off] : 0;
      __syncthreads();
      lds[t] += add;
      __syncthreads();
    }
    int run = lds[t] - s;                     // exclusive prefix
    if (t == 0) row_ptr[0] = 0;
    if (base + CH <= n) {
      const int4* p = (const int4*)(in_deg + base);
      int c4 = CH >> 2;
#pragma unroll 4
      for (int j = 0; j < c4; ++j) {
        int4 q = p[j];
        int i = base + j * 4;
        run += q.x; row_ptr[i + 1] = run;
        run += q.y; row_ptr[i + 2] = run;
        run += q.z; row_ptr[i + 3] = run;
        run += q.w; row_ptr[i + 4] = run;
      }
    } else {
      for (int i = base; i < n; ++i) { run += in_deg[i]; row_ptr[i + 1] = run; }
    }
    return;
  }

  // ============ GEMM roles (unified; only B source + epilogue differ) ============
  int bb = b - 1;
  bool isSeq = bb < gb;
  int m0 = (isSeq ? bb : bb - gb) * 128;
  const ushort* Bsrc = isSeq ? fcWb : W1T;
  int wave = t >> 6, lane = t & 63;
  int wm = wave * 32;
  int l15 = lane & 15, quad = lane >> 4;

  floatx4 acc[2][16];
#pragma unroll
  for (int i = 0; i < 2; ++i)
#pragma unroll
    for (int j = 0; j < 16; ++j) acc[i][j] = (floatx4)(0.f);

  for (int kc = 0; kc < 256; kc += 64) {
#pragma unroll
    for (int r = 0; r < 8; ++r) {   // A: features fp32 -> bf16 LDS (swizzled)
      int idx = t + r * 256;
      int row = idx >> 4;           // 0..127
      int c = (idx & 15) << 2;      // ushort offset 0..60
      int grow = m0 + row; if (grow > M - 1) grow = M - 1;
      float4 v = *(const float4*)(feat + (size_t)grow * 256 + kc + c);
      ushort4 o;
      o.x = f2bf(v.x); o.y = f2bf(v.y); o.z = f2bf(v.z); o.w = f2bf(v.w);
      int sc = c ^ ((row & 7) << 3);
      *(ushort4*)&A_lds[row * 64 + sc] = o;
    }
#pragma unroll
    for (int r = 0; r < 8; ++r) {   // B: bf16 copy (swizzled)
      int idx = t + r * 256;
      int row = idx >> 3;           // 0..255
      int c = (idx & 7) << 3;       // ushort offset 0..56
      int sc = c ^ ((row & 7) << 3);
      *(uint4*)&B_lds[row * 64 + sc] = *(const uint4*)(Bsrc + (size_t)row * 256 + kc + c);
    }
    __syncthreads();
#pragma unroll
    for (int ko = 0; ko < 2; ++ko) {
      short8 a[2];
#pragma unroll
      for (int i = 0; i < 2; ++i) {
        int row = wm + i * 16 + l15;
        int sc = (ko * 32 + quad * 8) ^ ((l15 & 7) << 3);   // row&7 == l15&7
        a[i] = *(const short8*)&A_lds[row * 64 + sc];
      }
#pragma unroll
      for (int j = 0; j < 16; ++j) {
        int brow = j * 16 + l15;
        int sc = (ko * 32 + quad * 8) ^ ((l15 & 7) << 3);
        short8 bv = *(const short8*)&B_lds[brow * 64 + sc];
#pragma unroll
        for (int i = 0; i < 2; ++i)
          acc[i][j] = __builtin_amdgcn_mfma_f32_16x16x32_bf16(a[i], bv, acc[i][j], 0, 0, 0);
      }
    }
    __syncthreads();
  }

  if (isSeq) {
#pragma unroll
    for (int i = 0; i < 2; ++i)
#pragma unroll
      for (int j = 0; j < 16; ++j) {
        int col = j * 16 + l15;
#pragma unroll
        for (int r = 0; r < 4; ++r) {
          int row = m0 + wm + i * 16 + quad * 4 + r;
          if (row < M) s_out[(size_t)row * 256 + col] = acc[i][j][r];
        }
      }
  } else {
#pragma unroll
    for (int i = 0; i < 2; ++i)
#pragma unroll
      for (int j = 0; j < 16; ++j) {
        int col = j * 16 + l15;
#pragma unroll
        for (int r = 0; r < 4; ++r) {
          int row = m0 + wm + i * 16 + quad * 4 + r;
          if (row < M) xw1_bf[(size_t)row * 256 + col] = f2bf(acc[i][j][r]);
        }
      }
  }
}

// ---- bucket edges by dst (CSR fill); 2 edges/thread; record {src, bits(rsqrt(out_deg))} ----
__global__ void fill_kernel(const int* __restrict__ src, const int* __restrict__ dst,
                            const int* __restrict__ row_ptr, int* __restrict__ fill_cnt,
                            const int* __restrict__ out_deg,
                            int2* __restrict__ edge_sw, int E) {
  int e = (blockIdx.x * 256 + threadIdx.x) * 2;
  if (e + 1 < E) {
    int2 s = *(const int2*)(src + e);
    int2 d = *(const int2*)(dst + e);
    int pos0 = row_ptr[d.x] + atomicAdd(&fill_cnt[d.x], 1);
    int od0 = out_deg[s.x]; if (od0 < 1) od0 = 1;
    int2 r0; r0.x = s.x; r0.y = __float_as_int(rsqrtf((float)od0));
    edge_sw[pos0] = r0;
    int pos1 = row_ptr[d.y] + atomicAdd(&fill_cnt[d.y], 1);
    int od1 = out_deg[s.y]; if (od1 < 1) od1 = 1;
    int2 r1; r1.x = s.y; r1.y = __float_as_int(rsqrtf((float)od1));
    edge_sw[pos1] = r1;
  } else if (e < E) {
    int d = dst[e]; int s = src[e];
    int pos = row_ptr[d] + atomicAdd(&fill_cnt[d], 1);
    int od = out_deg[s]; if (od < 1) od = 1;
    int2 r; r.x = s; r.y = __float_as_int(rsqrtf((float)od));
    edge_sw[pos] = r;
  }
}

// ---- aggregation over TRANSFORMED features with fused epilogue ----
// mode 0 (h):  out32[n][256] = relu(acc*inn + bias[dim]), outbf = bf16 copy
// mode 1 (z):  dims 0..127 = mean-part, 128..255 = logstd-part ->
//              z[n][c] = relu(am*inn+b2[c]) + noise[n][c]*exp(al*inn+b3[c])
__global__ __launch_bounds__(256) void agg_kernel(
    const ushort* __restrict__ x, const int* __restrict__ row_ptr,
    const int2* __restrict__ edge_sw,
    const float* __restrict__ bias, const float* __restrict__ noise,
    float* __restrict__ out32, ushort* __restrict__ outbf, int N, int mode) {
  int wave = threadIdx.x >> 6, lane = threadIdx.x & 63;
  int n = blockIdx.x * 4 + wave;
  if (n >= N) return;
  int half = lane >> 5;
  int hl = lane & 31;
  int start = row_ptr[n], end = row_ptr[n + 1];
  int dg = end - start; if (dg < 1) dg = 1;
  float inn = rsqrtf((float)dg);

  float acc[8];
#pragma unroll
  for (int k = 0; k < 8; ++k) acc[k] = 0.f;

  for (int base = start; base < end; base += 16) {
    int cs[8]; float cw[8];
    if (base + 16 <= end) {
#pragma unroll
      for (int k = 0; k < 8; ++k) {
        int2 e = edge_sw[base + half + 2 * k];
        cs[k] = e.x; cw[k] = __int_as_float(e.y);
      }
    } else {
#pragma unroll
      for (int k = 0; k < 8; ++k) {
        int i = base + half + 2 * k;
        cs[k] = 0; cw[k] = 0.f;
        if (i < end) { int2 e = edge_sw[i]; cs[k] = e.x; cw[k] = __int_as_float(e.y); }
      }
    }
    uint4 v[8];
#pragma unroll
    for (int k = 0; k < 8; ++k)
      v[k] = *(const uint4*)&x[(size_t)cs[k] * 256 + hl * 8];
#pragma unroll
    for (int k = 0; k < 8; ++k) {
      const uint32_t* p = (const uint32_t*)&v[k];
      float wk = cw[k];
#pragma unroll
      for (int q = 0; q < 4; ++q) {
        acc[2 * q]     += bf2f((ushort)(p[q] & 0xffffu)) * wk;
        acc[2 * q + 1] += bf2f((ushort)(p[q] >> 16)) * wk;
      }
    }
  }

#pragma unroll
  for (int k = 0; k < 8; ++k) acc[k] += __shfl_xor(acc[k], 32, 64);

  if (mode == 0) {
    if (half == 0) {
      int c0 = hl * 8;
      float4 ba = *(const float4*)(bias + c0);
      float4 bb = *(const float4*)(bias + c0 + 4);
      float h[8];
      h[0] = fmaxf(acc[0] * inn + ba.x, 0.f);
      h[1] = fmaxf(acc[1] * inn + ba.y, 0.f);
      h[2] = fmaxf(acc[2] * inn + ba.z, 0.f);
      h[3] = fmaxf(acc[3] * inn + ba.w, 0.f);
      h[4] = fmaxf(acc[4] * inn + bb.x, 0.f);
      h[5] = fmaxf(acc[5] * inn + bb.y, 0.f);
      h[6] = fmaxf(acc[6] * inn + bb.z, 0.f);
      h[7] = fmaxf(acc[7] * inn + bb.w, 0.f);
      *(float4*)&out32[(size_t)n * 256 + c0] = make_float4(h[0], h[1], h[2], h[3]);
      *(float4*)&out32[(size_t)n * 256 + c0 + 4] = make_float4(h[4], h[5], h[6], h[7]);
      uint4 ob; uint32_t* po = (uint32_t*)&ob;
#pragma unroll
      for (int q = 0; q < 4; ++q)
        po[q] = ((uint32_t)f2bf(h[2 * q + 1]) << 16) | (uint32_t)f2bf(h[2 * q]);
      *(uint4*)&outbf[(size_t)n * 256 + c0] = ob;
    }
  } else {
    float pacc[8];
#pragma unroll
    for (int k = 0; k < 8; ++k) pacc[k] = __shfl(acc[k], (lane & 15) + 16, 64);
    if (lane < 16) {
      int c0 = lane * 8;
      float4 b2a = *(const float4*)(bias + c0);
      float4 b2b = *(const float4*)(bias + c0 + 4);
      float4 b3a = *(const float4*)(bias + 128 + c0);
      float4 b3b = *(const float4*)(bias + 128 + c0 + 4);
      float4 nza = *(const float4*)(noise + (size_t)n * 128 + c0);
      float4 nzb = *(const float4*)(noise + (size_t)n * 128 + c0 + 4);
      float z[8];
      z[0] = fmaxf(acc[0] * inn + b2a.x, 0.f) + nza.x * expf(pacc[0] * inn + b3a.x);
      z[1] = fmaxf(acc[1] * inn + b2a.y, 0.f) + nza.y * expf(pacc[1] * inn + b3a.y);
      z[2] = fmaxf(acc[2] * inn + b2a.z, 0.f) + nza.z * expf(pacc[2] * inn + b3a.z);
      z[3] = fmaxf(acc[3] * inn + b2a.w, 0.f) + nza.w * expf(pacc[3] * inn + b3a.w);
      z[4] = fmaxf(acc[4] * inn + b2b.x, 0.f) + nzb.x * expf(pacc[4] * inn + b3b.x);
      z[5] = fmaxf(acc[5] * inn + b2b.y, 0.f) + nzb.y * expf(pacc[5] * inn + b3b.y);
      z[6] = fmaxf(acc[6] * inn + b2b.z, 0.f) + nzb.z * expf(pacc[6] * inn + b3b.z);
      z[7] = fmaxf(acc[7] * inn + b2b.w, 0.f) + nzb.w * expf(pacc[7] * inn + b3b.w);
      *(float4*)&out32[(size_t)n * 128 + c0] = make_float4(z[0], z[1], z[2], z[3]);
      *(float4*)&out32[(size_t)n * 128 + c0 + 4] = make_float4(z[4], z[5], z[6], z[7]);
    }
  }
}

// ---- MFMA GEMM: hwc = h_bf @ WcT, bf16 out, swizzled stride-64 LDS (48KB) ----
__global__ __launch_bounds__(256, 2) void gemm_bf_kernel(
    const ushort* __restrict__ A, const ushort* __restrict__ BT,
    ushort* __restrict__ Cbf, int M) {
  __shared__ alignas(16) ushort A_lds[128 * 64];
  __shared__ alignas(16) ushort B_lds[256 * 64];
  int t = threadIdx.x;
  int m0 = blockIdx.x * 128;
  int wave = t >> 6, lane = t & 63;
  int wm = wave * 32;
  int l15 = lane & 15, quad = lane >> 4;

  floatx4 acc[2][16];
#pragma unroll
  for (int i = 0; i < 2; ++i)
#pragma unroll
    for (int j = 0; j < 16; ++j) acc[i][j] = (floatx4)(0.f);

  for (int kc = 0; kc < 256; kc += 64) {
#pragma unroll
    for (int r = 0; r < 4; ++r) {         // A: 128 rows x 8 granules (swizzled)
      int idx = t + r * 256;
      int row = idx >> 3;
      int c = (idx & 7) << 3;
      int grow = m0 + row; if (grow > M - 1) grow = M - 1;
      int sc = c ^ ((row & 7) << 3);
      *(uint4*)&A_lds[row * 64 + sc] = *(const uint4*)(A + (size_t)grow * 256 + kc + c);
    }
#pragma unroll
    for (int r = 0; r < 8; ++r) {         // B: 256 rows x 8 granules (swizzled)
      int idx = t + r * 256;
      int row = idx >> 3;
      int c = (idx & 7) << 3;
      int sc = c ^ ((row & 7) << 3);
      *(uint4*)&B_lds[row * 64 + sc] = *(const uint4*)(BT + (size_t)row * 256 + kc + c);
    }
    __syncthreads();
#pragma unroll
    for (int ko = 0; ko < 2; ++ko) {
      short8 a[2];
#pragma unroll
      for (int i = 0; i < 2; ++i) {
        int row = wm + i * 16 + l15;
        int sc = (ko * 32 + quad * 8) ^ ((l15 & 7) << 3);
        a[i] = *(const short8*)&A_lds[row * 64 + sc];
      }
#pragma unroll
      for (int j = 0; j < 16; ++j) {
        int brow = j * 16 + l15;
        int sc = (ko * 32 + quad * 8) ^ ((l15 & 7) << 3);
        short8 bv = *(const short8*)&B_lds[brow * 64 + sc];
#pragma unroll
        for (int i = 0; i < 2; ++i)
          acc[i][j] = __builtin_amdgcn_mfma_f32_16x16x32_bf16(a[i], bv, acc[i][j], 0, 0, 0);
      }
    }
    __syncthreads();
  }

#pragma unroll
  for (int i = 0; i < 2; ++i)
#pragma unroll
    for (int j = 0; j < 16; ++j) {
      int col = j * 16 + l15;
#pragma unroll
      for (int r = 0; r < 4; ++r) {
        int row = m0 + wm + i * 16 + quad * 4 + r;
        if (row < M) Cbf[(size_t)row * 256 + col] = f2bf(acc[i][j][r]);
      }
    }
}

extern "C" void kernel_launch(void* const* d_in, const int* in_sizes, int n_in,
                              void* d_out, int out_size, void* d_ws, size_t ws_size,
                              hipStream_t stream) {
  const float* features = (const float*)d_in[0];
  const float* noise    = (const float*)d_in[1];
  const float* W1 = (const float*)d_in[2];
  const float* b1 = (const float*)d_in[3];
  const float* W2 = (const float*)d_in[4];
  const float* b2 = (const float*)d_in[5];
  const float* W3 = (const float*)d_in[6];
  const float* b3 = (const float*)d_in[7];
  const float* fcW = (const float*)d_in[8];
  const int* src = (const int*)d_in[9];
  const int* dst = (const int*)d_in[10];
  const int N = in_sizes[0] / IN_DIM;
  const int E = in_sizes[9];

  float* out = (float*)d_out;
  float* z_out = out;                           // N x 128
  float* h_out = out + (size_t)N * OUT_DIM;     // N x 256
  float* s_out = h_out + (size_t)N * HID_DIM;   // N x 256

  char* w = (char*)d_ws;
  auto carve = [&](size_t bytes) {
    char* p = w;
    w += (bytes + 255) & ~(size_t)255;
    return p;
  };
  ushort* xw1_bf = (ushort*)carve((size_t)N * 256 * 2);
  ushort* h_bf   = (ushort*)carve((size_t)N * 256 * 2);
  ushort* hwc_bf = (ushort*)carve((size_t)N * 256 * 2);
  ushort* W1T  = (ushort*)carve(256 * 256 * 2);
  ushort* WcT  = (ushort*)carve(256 * 256 * 2);
  ushort* fcWb = (ushort*)carve(256 * 256 * 2);
  float*  bcat = (float*)carve(256 * 4);
  int* degs    = (int*)carve((size_t)3 * N * 4);          // out_deg | in_deg | fill_cnt
  int* out_deg = degs;
  int* in_deg  = degs + N;
  int* fill_cnt = degs + 2 * N;
  int* row_ptr  = (int*)carve((size_t)(N + 1) * 4);
  int2* edge_sw = (int2*)carve((size_t)E * 8);

  hipMemsetAsync(degs, 0, (size_t)3 * N * 4, stream);
  int eblocks = ((E + 1) / 2 + 255) / 256;
  int gb = (N + 127) / 128;

  // A: degree atomics || W1T/WcT/bcat prep || fcW bf16 convert (all independent)
  deg_prep_kernel<<<eblocks + 512, 256, 0, stream>>>(src, dst, out_deg, in_deg, E, eblocks,
                                                     W1, W2, W3, b2, b3, fcW,
                                                     W1T, WcT, bcat, fcWb);
  // MEGA: scan || seq_fts GEMM || XW1 GEMM (W1T/fcWb ready from A)
  mega_kernel<<<2 * gb + 1, 256, 0, stream>>>(features, fcWb, W1T, s_out, xw1_bf,
                                              in_deg, row_ptr, N, N, gb);
  // CSR fill (needs row_ptr + out_deg)
  fill_kernel<<<eblocks, 256, 0, stream>>>(src, dst, row_ptr, fill_cnt, out_deg,
                                           edge_sw, E);
  // layer 1: h = relu(inn * agg(xw1) + b1)
  agg_kernel<<<(N + 3) / 4, 256, 0, stream>>>(xw1_bf, row_ptr, edge_sw, b1,
                                              (const float*)nullptr, h_out, h_bf, N, 0);
  // layer 2 dense part: hwc = h_bf @ [W2|W3]
  gemm_bf_kernel<<<gb, 256, 0, stream>>>(h_bf, WcT, hwc_bf, N);
  // layer 2 + reparam: z = relu(inn*agg(hwc_m)+b2) + noise*exp(inn*agg(hwc_l)+b3)
  agg_kernel<<<(N + 3) / 4, 256, 0, stream>>>(hwc_bf, row_ptr, edge_sw, bcat,
                                              noise, z_out, (ushort*)nullptr, N, 1);
}